// Round 11
// baseline (727.623 us; speedup 1.0000x reference)
//
#include <hip/hip_runtime.h>
#include <math.h>

#define Bsz 8
#define Dd  128
#define Tt  4096
#define Kk  1024
#define NQ  8
#define BT  (Bsz*Tt)        // 32768 points
#define MT  64              // points per block (4 waves x 16)
#define DELTA 0.05f         // >= 10x rigorous |approx-exact| score bound

typedef float f32x4 __attribute__((ext_vector_type(4)));
typedef short short8 __attribute__((ext_vector_type(8)));

__device__ __forceinline__ unsigned short f2bf(float x) {   // RNE f32->bf16
    unsigned u = __float_as_uint(x);
    u += 0x7FFF + ((u >> 16) & 1);
    return (unsigned short)(u >> 16);
}
__device__ __forceinline__ float bf2f(unsigned short h) {
    return __uint_as_float(((unsigned)h) << 16);
}

// ---------------------------------------------------------------------------
// init: transpose x (B,D,T) -> resid (B,T,D)
// ---------------------------------------------------------------------------
__global__ void k_init(const float* __restrict__ x,
                       float* __restrict__ resid) {
    __shared__ float tile[32][33];
    int b  = blockIdx.z;
    int t0 = blockIdx.x * 32, d0 = blockIdx.y * 32;
    int tx = threadIdx.x, ty = threadIdx.y;   // 32 x 8
    #pragma unroll
    for (int k = 0; k < 4; k++) {
        int d = d0 + ty + k * 8;
        tile[ty + k * 8][tx] = x[((size_t)(b * Dd + d)) * Tt + t0 + tx];
    }
    __syncthreads();
    #pragma unroll
    for (int k = 0; k < 4; k++) {
        int t = t0 + ty + k * 8;
        resid[((size_t)(b * Tt + t)) * Dd + d0 + tx] = tile[tx][ty + k * 8];
    }
}

// ---------------------------------------------------------------------------
// k_prep: split codebook into hi/lo bf16, pre-swizzled into MFMA B-fragment
// order. B-frag (16x16x32 bf16): lane holds col n=lane&15, k=quad*8+j.
// Layout per (q, tile): 8192 B = [ch kc0..3 (1KB each) | cl kc0..3].
// ---------------------------------------------------------------------------
__global__ void k_prep(const float* __restrict__ cb, char* __restrict__ bswz) {
    int ln = threadIdx.x;                 // 64
    int kc = blockIdx.x & 3;
    int t  = (blockIdx.x >> 2) & 63;
    int q  = blockIdx.x >> 8;
    int code = t * 16 + (ln & 15);
    int d0   = kc * 32 + (ln >> 4) * 8;
    const float* src = cb + ((size_t)(q * Kk + code)) * Dd + d0;
    float v[8];
    *(float4*)&v[0] = *(const float4*)src;
    *(float4*)&v[4] = *(const float4*)(src + 4);
    short8 h, l;
    #pragma unroll
    for (int j = 0; j < 8; j++) {
        unsigned short hu = f2bf(v[j]);
        h[j] = (short)hu;
        l[j] = (short)f2bf(v[j] - bf2f(hu));   // exact remainder, then RNE
    }
    char* base = bswz + ((size_t)(q * 64 + t)) * 8192;
    *(short8*)(base + kc * 1024 + ln * 16) = h;
    *(short8*)(base + 4096 + kc * 1024 + ln * 16) = l;
}

// ---------------------------------------------------------------------------
// c2[q][k] = sum_d cb[q][k][d]^2 (exact f32) ; zero commit accumulators
// ---------------------------------------------------------------------------
__global__ void k_c2(const float* __restrict__ cb,
                     float* __restrict__ c2,
                     double* __restrict__ commits) {
    int row  = blockIdx.x * 4 + (threadIdx.x >> 6);
    int lane = threadIdx.x & 63;
    const float* p = cb + (size_t)row * Dd;
    float a = p[lane], b = p[lane + 64];
    float s = a * a + b * b;
    #pragma unroll
    for (int off = 32; off; off >>= 1) s += __shfl_down(s, off);
    if (lane == 0) c2[row] = s;
    if (blockIdx.x == 0 && threadIdx.x < NQ) commits[threadIdx.x] = 0.0;
}

// exact f32 chain, d ascending — identical to the validated round-6 order
__device__ __forceinline__ float exact_score(const float* __restrict__ rrow,
                                             const float* __restrict__ crow,
                                             float c2v) {
    float a = 0.0f;
    #pragma unroll
    for (int d4 = 0; d4 < 32; d4++) {
        float4 r = *(const float4*)(rrow + d4 * 4);
        float4 c = *(const float4*)(crow + d4 * 4);
        a = fmaf(r.x, c.x, a); a = fmaf(r.y, c.y, a);
        a = fmaf(r.z, c.z, a); a = fmaf(r.w, c.w, a);
    }
    return fmaf(-2.0f, a, c2v);
}

// ---------------------------------------------------------------------------
// MFMA argmin: single pass over 64 tiles, LDS double-buffered B-fragments
// (round-9 loop) + per-lane top-3 / cross-lane merge / certified <=2-cand
// exact rescore (round-10 epilogue). Block = 256 thr = 4 waves; 64 pts.
// Certification: after merge, if global b3 > b1+DELTA then every code with
// approx score <= b1+DELTA (superset of exact argmin + ties) is in {i1,i2};
// exact f32 rescore with index tie-break => codes exact by construction.
// Else: rare block-cooperative exact scan.
// ---------------------------------------------------------------------------
__global__ __launch_bounds__(256, 2) void k_argmin_mfma(
        float* resid,
        const float*  __restrict__ cb,     // (K x D) f32 this stage
        const float4* __restrict__ bswzq,  // swizzled split frags this stage
        const float*  __restrict__ c2g,    // (K) exact f32
        float* __restrict__ codes_f,       // offset by q*BT
        double* __restrict__ commit) {
    __shared__ float4 Bst[2][512];         // double-buffered tile frags 16KB
    __shared__ float  c2s[Kk];             // 4KB
    __shared__ float  fb1[MT], fb2[MT], fb3[MT];
    __shared__ int    fi1[MT], fi2[MT];
    __shared__ int    sidxs[MT];
    __shared__ int    nfall, flist[MT];
    __shared__ float  fwv[4]; __shared__ int fwi[4];
    __shared__ float  csum[4];

    int tid  = threadIdx.x;
    int w    = tid >> 6, ln = tid & 63;
    int quad = ln >> 4,  m  = ln & 15;
    int base = blockIdx.x * MT;

    for (int i = tid; i < Kk; i += 256) c2s[i] = c2g[i];
    if (tid == 0) nfall = 0;

    // A-fragments for this wave's 16 points: A[m=lane&15][k=quad*8+j]
    short8 Ah[4], Al[4];
    {
        const float* rrow = resid + ((size_t)(base + w * 16 + m)) * Dd;
        #pragma unroll
        for (int kc = 0; kc < 4; kc++) {
            int d0 = kc * 32 + quad * 8;
            float v[8];
            *(float4*)&v[0] = *(const float4*)(rrow + d0);
            *(float4*)&v[4] = *(const float4*)(rrow + d0 + 4);
            short8 h, l;
            #pragma unroll
            for (int j = 0; j < 8; j++) {
                unsigned short hu = f2bf(v[j]);
                h[j] = (short)hu;
                l[j] = (short)f2bf(v[j] - bf2f(hu));
            }
            Ah[kc] = h; Al[kc] = l;
        }
    }

    // prestage tile 0
    Bst[0][tid]       = bswzq[tid];
    Bst[0][tid + 256] = bswzq[tid + 256];
    __syncthreads();

    // per-lane top-3 state per j-slot (4 points per lane)
    float b1[4], b2[4], b3[4]; int i1[4], i2[4];
    #pragma unroll
    for (int j = 0; j < 4; j++) {
        b1[j] = INFINITY; b2[j] = INFINITY; b3[j] = INFINITY;
        i1[j] = 0; i2[j] = 0;
    }

    for (int t = 0; t < 64; t++) {
        int buf = t & 1;
        bool more = (t < 63);
        float4 g0, g1;
        if (more) {                         // load next tile into registers
            const float4* src = bswzq + (size_t)(t + 1) * 512;
            g0 = src[tid]; g1 = src[tid + 256];
        }
        const short8* Bp = (const short8*)&Bst[buf][0];
        f32x4 acc01 = {0.f, 0.f, 0.f, 0.f};
        f32x4 acc23 = {0.f, 0.f, 0.f, 0.f};
        #pragma unroll
        for (int kc = 0; kc < 4; kc++) {
            short8 ch = Bp[kc * 64 + ln];
            short8 cl = Bp[256 + kc * 64 + ln];
            if (kc < 2) {
                acc01 = __builtin_amdgcn_mfma_f32_16x16x32_bf16(Al[kc], ch, acc01, 0, 0, 0);
                acc01 = __builtin_amdgcn_mfma_f32_16x16x32_bf16(Ah[kc], cl, acc01, 0, 0, 0);
                acc01 = __builtin_amdgcn_mfma_f32_16x16x32_bf16(Ah[kc], ch, acc01, 0, 0, 0);
            } else {
                acc23 = __builtin_amdgcn_mfma_f32_16x16x32_bf16(Al[kc], ch, acc23, 0, 0, 0);
                acc23 = __builtin_amdgcn_mfma_f32_16x16x32_bf16(Ah[kc], cl, acc23, 0, 0, 0);
                acc23 = __builtin_amdgcn_mfma_f32_16x16x32_bf16(Ah[kc], ch, acc23, 0, 0, 0);
            }
        }
        float c2v = c2s[t * 16 + m];
        int   code = t * 16 + m;               // ascending in t per lane
        #pragma unroll
        for (int j = 0; j < 4; j++) {
            float s = fmaf(-2.0f, acc01[j] + acc23[j], c2v);
            bool lt1 = s < b1[j];
            bool lt2 = s < b2[j];
            float t1 = fmaxf(b1[j], s);
            b3[j] = fminf(b3[j], fmaxf(b2[j], t1));
            i2[j] = lt1 ? i1[j] : (lt2 ? code : i2[j]);
            b2[j] = fminf(b2[j], t1);
            i1[j] = lt1 ? code : i1[j];
            b1[j] = fminf(b1[j], s);
        }
        if (more) {
            Bst[buf ^ 1][tid]       = g0;
            Bst[buf ^ 1][tid + 256] = g1;
        }
        __syncthreads();
    }

    // cross-lane merge of sorted triples over the 16 cols (xor 1,2,4,8)
    #pragma unroll
    for (int j = 0; j < 4; j++) {
        float v1 = b1[j], v2 = b2[j], v3 = b3[j];
        int   a1 = i1[j], a2 = i2[j];
        #pragma unroll
        for (int off = 1; off < 16; off <<= 1) {
            float w1 = __shfl_xor(v1, off); int j1 = __shfl_xor(a1, off);
            float w2 = __shfl_xor(v2, off); int j2 = __shfl_xor(a2, off);
            float w3 = __shfl_xor(v3, off);
            bool aw = (v1 < w1) || (v1 == w1 && a1 < j1);
            float x1 = aw ? v1 : w1, x2 = aw ? v2 : w2, x3 = aw ? v3 : w3;
            int   y1 = aw ? a1 : j1, y2 = aw ? a2 : j2;
            float z1 = aw ? w1 : v1, z2 = aw ? w2 : v2;
            int   u1 = aw ? j1 : a1;
            bool s2a = (x2 < z1) || (x2 == z1 && y2 < u1);
            v1 = x1; a1 = y1;
            v2 = s2a ? x2 : z1; a2 = s2a ? y2 : u1;
            v3 = s2a ? fminf(x3, z1) : fminf(x2, z2);
        }
        if (m == 0) {
            int p = w * 16 + quad * 4 + j;
            fb1[p] = v1; fb2[p] = v2; fb3[p] = v3;
            fi1[p] = a1; fi2[p] = a2;
        }
    }
    __syncthreads();

    // decision + exact rescore of <=2 candidates (thread per point)
    if (tid < MT) {
        int p = tid;
        float v1 = fb1[p], v2 = fb2[p], v3 = fb3[p];
        int   a1 = fi1[p], a2 = fi2[p];
        if (v3 <= v1 + DELTA) {
            int sl = atomicAdd(&nfall, 1);     // rare: >=3 in window
            flist[sl] = p;
        } else {
            int bk = a1;
            if (v2 <= v1 + DELTA) {            // two candidates: rescore both
                const float* rrow = resid + ((size_t)(base + p)) * Dd;
                float s1 = exact_score(rrow, cb + (size_t)a1 * Dd, c2s[a1]);
                float s2 = exact_score(rrow, cb + (size_t)a2 * Dd, c2s[a2]);
                if (s2 < s1 || (s2 == s1 && a2 < a1)) bk = a2;
            }
            sidxs[p] = bk;
            codes_f[base + p] = (float)bk;
        }
    }
    __syncthreads();

    // fallback: block-cooperative exact scan (executes ~never; must be exact)
    for (int fi = 0; fi < nfall; fi++) {
        int p = flist[fi];
        const float* rrow = resid + ((size_t)(base + p)) * Dd;
        float bv = INFINITY; int bk = 0;
        #pragma unroll
        for (int c = 0; c < 4; c++) {
            int k = tid * 4 + c;               // ascending within thread
            float sc = exact_score(rrow, cb + (size_t)k * Dd, c2s[k]);
            if (sc < bv || (sc == bv && k < bk)) { bv = sc; bk = k; }
        }
        #pragma unroll
        for (int off = 32; off; off >>= 1) {
            float v2 = __shfl_xor(bv, off);
            int   k2 = __shfl_xor(bk, off);
            if (v2 < bv || (v2 == bv && k2 < bk)) { bv = v2; bk = k2; }
        }
        if (ln == 0) { fwv[w] = bv; fwi[w] = bk; }
        __syncthreads();
        if (tid == 0) {
            float v = fwv[0]; int k = fwi[0];
            #pragma unroll
            for (int w2 = 1; w2 < 4; w2++) {
                if (fwv[w2] < v || (fwv[w2] == v && fwi[w2] < k)) {
                    v = fwv[w2]; k = fwi[w2];
                }
            }
            sidxs[p] = k;
            codes_f[base + p] = (float)k;
        }
        __syncthreads();
    }
    __syncthreads();

    // fused STE update: thread -> point tid>>2, dims [(tid&3)*32, +32)
    {
        int p = tid >> 2, dbeg = (tid & 3) * 32;
        float* rrow = resid + ((size_t)(base + p)) * Dd + dbeg;
        const float* qrow = cb + ((size_t)sidxs[p]) * Dd + dbeg;
        float cacc = 0.0f;
        #pragma unroll
        for (int hh = 0; hh < 8; hh++) {
            float4 r  = *(const float4*)(rrow + hh * 4);
            float4 qv = *(const float4*)(qrow + hh * 4);
            float t1x = qv.x - r.x, t1y = qv.y - r.y;
            float t1z = qv.z - r.z, t1w = qv.w - r.w;    // q - residual
            float qsx = r.x + t1x, qsy = r.y + t1y;
            float qsz = r.z + t1z, qsw = r.w + t1w;      // straight-through
            float4 nr = make_float4(r.x - qsx, r.y - qsy, r.z - qsz, r.w - qsw);
            *(float4*)(rrow + hh * 4) = nr;
            cacc = fmaf(t1x, t1x, cacc); cacc = fmaf(t1y, t1y, cacc);
            cacc = fmaf(t1z, t1z, cacc); cacc = fmaf(t1w, t1w, cacc);
        }
        #pragma unroll
        for (int off = 32; off; off >>= 1) cacc += __shfl_down(cacc, off);
        if (ln == 0) csum[w] = cacc;
    }
    __syncthreads();
    if (tid == 0)
        atomicAdd(commit, (double)(csum[0] + csum[1] + csum[2] + csum[3]));
}

// ---------------------------------------------------------------------------
// final: out(B,D,T) = x - resid_final^T
// ---------------------------------------------------------------------------
__global__ void k_final(const float* __restrict__ x,
                        const float* __restrict__ resid,
                        float* __restrict__ outq) {
    __shared__ float tile[32][33];
    int b  = blockIdx.z;
    int t0 = blockIdx.x * 32, d0 = blockIdx.y * 32;
    int tx = threadIdx.x, ty = threadIdx.y;   // 32 x 8
    #pragma unroll
    for (int k = 0; k < 4; k++) {
        int t = t0 + ty + k * 8;
        tile[ty + k * 8][tx] = resid[((size_t)(b * Tt + t)) * Dd + d0 + tx];
    }
    __syncthreads();
    #pragma unroll
    for (int k = 0; k < 4; k++) {
        int d = d0 + ty + k * 8;
        size_t o = ((size_t)(b * Dd + d)) * Tt + t0 + tx;
        outq[o] = x[o] - tile[tx][ty + k * 8];
    }
}

// ---------------------------------------------------------------------------
// scalars: bw = n_q * log2(K) * frame_rate ; penalty = mean(commits)
// ---------------------------------------------------------------------------
__global__ void k_scalars(const double* __restrict__ commits,
                          const int* __restrict__ frame_rate,
                          float* __restrict__ outs) {
    if (threadIdx.x == 0 && blockIdx.x == 0) {
        double s = 0.0;
        #pragma unroll
        for (int q = 0; q < NQ; q++) s += commits[q];
        double per_elem = s / ((double)NQ * (double)BT * (double)Dd);
        outs[0] = (float)(NQ * 10.0 * (double)frame_rate[0]); // log2(1024)=10
        outs[1] = (float)per_elem;
    }
}

extern "C" void kernel_launch(void* const* d_in, const int* in_sizes, int n_in,
                              void* d_out, int out_size, void* d_ws, size_t ws_size,
                              hipStream_t stream) {
    const float* x  = (const float*)d_in[0];   // (B, D, T)
    const float* cb = (const float*)d_in[1];   // (NQ, K, D)
    const int*   fr = (const int*)d_in[2];     // frame_rate

    float* outq    = (float*)d_out;                       // (B,D,T) 4194304
    float* codes_f = outq + (size_t)Bsz * Dd * Tt;        // (NQ,B,T) 262144
    float* scal    = codes_f + (size_t)NQ * BT;           // bw, penalty

    char* ws = (char*)d_ws;
    float*  resid   = (float*)ws;                              // BT*D f32
    float*  c2      = resid + (size_t)BT * Dd;                 // NQ*K f32
    double* commits = (double*)(c2 + (size_t)NQ * Kk);         // NQ f64
    char*   bswz    = (char*)(commits + NQ);                   // NQ*64*8192 B

    dim3 tb(32, 8, 1);
    k_init<<<dim3(Tt / 32, Dd / 32, Bsz), tb, 0, stream>>>(x, resid);
    k_prep<<<NQ * 256, 64, 0, stream>>>(cb, bswz);
    k_c2<<<NQ * Kk / 4, 256, 0, stream>>>(cb, c2, commits);

    for (int q = 0; q < NQ; q++) {
        k_argmin_mfma<<<BT / MT, 256, 0, stream>>>(
            resid,
            cb + (size_t)q * Kk * Dd,
            (const float4*)(bswz + (size_t)q * 64 * 8192),
            c2 + (size_t)q * Kk,
            codes_f + (size_t)q * BT,
            commits + q);
    }

    k_final<<<dim3(Tt / 32, Dd / 32, Bsz), tb, 0, stream>>>(x, resid, outq);
    k_scalars<<<1, 64, 0, stream>>>(commits, fr, scal);
}